// Round 13
// baseline (2483.365 us; speedup 1.0000x reference)
//
#include <hip/hip_runtime.h>
#include <stdint.h>

typedef _Float16 f16x8 __attribute__((ext_vector_type(8)));
typedef _Float16 f16x4 __attribute__((ext_vector_type(4)));
typedef float    f32x4 __attribute__((ext_vector_type(4)));
typedef unsigned int u32x4v __attribute__((ext_vector_type(4)));

#define T_LEN 512
#define RLX   __ATOMIC_RELAXED
#define AGT   __HIP_MEMORY_SCOPE_AGENT

union PK4 { _Float16 h[4]; unsigned long long q; };
union QZ  { unsigned long long q; f16x4 v; };

// ---------------------------------------------------------------------------
// async global->LDS (16B/lane). LDS dest = wave-uniform base + lane*16.
// GLOBAL SOURCE IS PER-LANE.
// ---------------------------------------------------------------------------
__device__ __forceinline__ void gload_lds16(const void* gsrc, void* ldsdst) {
    auto g = (const __attribute__((address_space(1))) void*)(reinterpret_cast<uintptr_t>(gsrc));
    auto s = (__attribute__((address_space(3))) void*)(reinterpret_cast<uintptr_t>(ldsdst));
    __builtin_amdgcn_global_load_lds(g, s, 16, 0, 0);
}

// ---------------------------------------------------------------------------
// prep: f16 weights (Wci=[W_iz;W_in], Whc=[W_hz;W_hn]), bc=b_i+b_h,
// zero tagged hbuf (tag 0 = step-0 seed, h_0=0). Runs every launch (replays).
// ---------------------------------------------------------------------------
__global__ __launch_bounds__(256) void prep_misc(
    const float* __restrict__ W_iz, const float* __restrict__ W_in,
    const float* __restrict__ W_hz, const float* __restrict__ W_hn,
    const float* __restrict__ b_iz, const float* __restrict__ b_in,
    const float* __restrict__ b_hz, const float* __restrict__ b_hn,
    _Float16* __restrict__ Wci, _Float16* __restrict__ Whc,
    float* __restrict__ bc, unsigned int* __restrict__ hbuf32)
{
    const int tid = blockIdx.x * 256 + threadIdx.x;
    if (tid < 131072) {                      // 2 * 1024*512/8 weight vec units
        const bool is_h = tid >= 65536;
        const int u = tid & 65535;
        const int e = u * 8;
        const int row = e >> 9;
        const int k = e & 511;
        const float* s;
        if (!is_h) s = (row < 512) ? (W_iz + (size_t)row * 512 + k)
                                   : (W_in + (size_t)(row - 512) * 512 + k);
        else       s = (row < 512) ? (W_hz + (size_t)row * 512 + k)
                                   : (W_hn + (size_t)(row - 512) * 512 + k);
        f32x4 a = *(const f32x4*)s;
        f32x4 b = *(const f32x4*)(s + 4);
        f16x8 o;
        o[0] = (_Float16)a[0]; o[1] = (_Float16)a[1];
        o[2] = (_Float16)a[2]; o[3] = (_Float16)a[3];
        o[4] = (_Float16)b[0]; o[5] = (_Float16)b[1];
        o[6] = (_Float16)b[2]; o[7] = (_Float16)b[3];
        _Float16* d = is_h ? Whc : Wci;
        *(f16x8*)(d + e) = o;
    } else if (tid < 132096) {               // 1024 combined biases
        const int j2 = tid - 131072;
        bc[j2] = (j2 < 512) ? (b_iz[j2] + b_hz[j2]) : (b_in[j2 - 512] + b_hn[j2 - 512]);
    } else if (tid < 164864) {               // zero tagged hbuf: 131072 u32 / 4
        const int u = tid - 132096;
        u32x4v z = {0u, 0u, 0u, 0u};
        *(u32x4v*)(hbuf32 + (size_t)u * 4) = z;
    }
}

// ---------------------------------------------------------------------------
// Phase 1: input projections -> BLOCKED izin records (f16, into d_out):
//   record (t, blk_s) = 2KB at byte (t*128+blk_s)*2048: [z 1KB][n 1KB];
//   in-gate: lane l (64) x 16B = [quad j0+4*(l>>4), quad j0+16+4*(l>>4)],
//   b = 16*(blk_s>>4) + (l&15), j0 = 32*(blk_s&15).
// (UNCHANGED — verified rounds 4/6/8-12.)
// ---------------------------------------------------------------------------
__global__ __launch_bounds__(256) void gemm_proj(
    const float* __restrict__ A,      // seq [65536][512] f32 (row = t*128+b)
    const _Float16* __restrict__ Bw,  // Wci [1024][512] f16
    const float* __restrict__ bc,     // [1024] f32
    _Float16* Co)                     // blocked izin (= d_out as f16)
{
    __shared__ _Float16 As[128 * 40];   // padded stride 40 f16
    __shared__ _Float16 Bs[128 * 32];   // linear (global_load_lds target)

    const int mt = blockIdx.x;          // = t
    const int nt = blockIdx.y;          // 0..7 (0-3: z gate, 4-7: n gate)
    const int m0 = mt * 128, n0 = nt * 128;
    const int tid = threadIdx.x;
    const int w = tid >> 6, l = tid & 63;
    const int wr = w >> 1, wc = w & 1;
    const int lrow = l & 15, lk = l >> 4;

    f32x4 acc[4][4] = {};

    const int arow = tid >> 1;
    const int acol = (tid & 1) * 16;

    for (int kt = 0; kt < 16; ++kt) {
        const int k0 = kt * 32;
        if (kt) __syncthreads();
        const float* as = A + (size_t)(m0 + arow) * 512 + k0 + acol;
        f32x4 a0 = *(const f32x4*)as;
        f32x4 a1 = *(const f32x4*)(as + 4);
        f32x4 a2 = *(const f32x4*)(as + 8);
        f32x4 a3 = *(const f32x4*)(as + 12);
        f16x8 h0, h1;
#pragma unroll
        for (int e = 0; e < 4; ++e) {
            h0[e] = (_Float16)a0[e]; h0[4 + e] = (_Float16)a1[e];
            h1[e] = (_Float16)a2[e]; h1[4 + e] = (_Float16)a3[e];
        }
        *(f16x8*)&As[arow * 40 + acol] = h0;
        *(f16x8*)&As[arow * 40 + acol + 8] = h1;
#pragma unroll
        for (int i = 0; i < 2; ++i) {
            const int chunk = w * 2 + i;
            const _Float16* gsrc =
                Bw + (size_t)(n0 + chunk * 16 + (l >> 2)) * 512 + k0 + (l & 3) * 8;
            gload_lds16(gsrc, &Bs[chunk * 512]);
        }
        __syncthreads();
        f16x8 af[4], bf[4];
#pragma unroll
        for (int i = 0; i < 4; ++i) {
            af[i] = *(const f16x8*)&As[(wr * 64 + i * 16 + lrow) * 40 + lk * 8];
            bf[i] = *(const f16x8*)&Bs[(wc * 64 + i * 16 + lrow) * 32 + lk * 8];
        }
#pragma unroll
        for (int mi = 0; mi < 4; ++mi)
#pragma unroll
            for (int ni = 0; ni < 4; ++ni)
                acc[mi][ni] = __builtin_amdgcn_mfma_f32_16x16x32_f16(
                    bf[ni], af[mi], acc[mi][ni], 0, 0, 0);
    }
    // epilogue: bias + cvt f16 + blocked store
    const int gate = nt >> 2;
#pragma unroll
    for (int mi = 0; mi < 4; ++mi) {
#pragma unroll
        for (int p = 0; p < 2; ++p) {
            const int j2q0 = n0 + wc * 64 + p * 32 + 4 * lk;
            const f32x4 b0 = *(const f32x4*)&bc[j2q0];
            const f32x4 b1 = *(const f32x4*)&bc[j2q0 + 16];
            f16x8 o;
#pragma unroll
            for (int r = 0; r < 4; ++r) {
                o[r]     = (_Float16)(acc[mi][2 * p][r]     + b0[r]);
                o[4 + r] = (_Float16)(acc[mi][2 * p + 1][r] + b1[r]);
            }
            const int blk_s = (wr * 4 + mi) * 16 + (nt & 3) * 4 + wc * 2 + p;
            _Float16* dst = Co + ((((size_t)mt * 128 + blk_s) * 2 + gate) * 512) + l * 8;
            *(f16x8*)dst = o;
        }
    }
}

// ---------------------------------------------------------------------------
// Phase 2: persistent scan — 128 WGs x 2 waves (128 thr).
// g = blk&7 (batch rows [16g,+16)); slot = blk>>3 in [0,16) (j-cols
// [32*slot,+32)); wave wv in {0,1} owns j-tile [32*slot+16*wv,+16), both
// gates. A group's 16 WGs are blk ≡ g (mod 8) -> same XCD (round-robin).
// WEIGHTS IN LDS (64 KB, R6's verified conflict-free subtile pattern):
// rounds 9-12 proved the compiler won't keep them in VGPRs (spill/remat),
// and at 32 WGs the per-CU weight re-read (256 KB/step through L2/scratch)
// was the hidden ~1.5 us/step. 128 CUs x LDS -> 96 KB/CU-step at LDS BW.
// h exchange: tagged u32 (unchanged protocol, 15 partners): burst 15 pairs,
// fused retry, unpack -> swizzled hlds, sync, MFMA, gates, own stage,
// counted vmcnt, fire-and-forget publish, H store. Safety as before:
// record index 16g+slot partitions by group (cross-group H writes touch
// only own group's records); two-parity tag induction bounds intra-group
// skew (all pairs mutually wait).
// ---------------------------------------------------------------------------
__global__ __launch_bounds__(128, 1) void gru_scan(
    const _Float16* __restrict__ Whc,   // [1024][512] f16
    const char* izb,                    // d_out bytes: blocked izin (aliases Hout)
    float* Hout,                        // d_out as f32 [t][b][j]
    unsigned int* hbuf32)               // [2][128][512] tagged u32
{
    __shared__ _Float16 wlds[64 * 512];       // 64 KB: (wv,gate,s) subtiles x 1KB
    __shared__ _Float16 hlds[2 * 16 * 512];   // 32 KB, XOR-swizzled (^(b&7)<<3)

    const int blk  = blockIdx.x;        // 0..127
    const int g    = blk & 7;
    const int slot = blk >> 3;          // 0..15
    const int tid  = threadIdx.x;       // 0..127
    const int wv   = tid >> 6;          // wave 0..1
    const int l    = tid & 63;
    const int lrow = l & 15, lk = l >> 4;
    const int j0   = slot * 32;
    const int jq   = j0 + wv * 16 + 4 * lk;      // lane's j quad base
    const int bg   = 16 * g + lrow;              // lane's global b
    const int blk_s = 16 * g + slot;             // THE izin record for this WG
    const int stage_b = tid >> 3;                // 0..15 (partner staging b)
    const int stage_j = (tid & 7) * 4;           // 0..28 (j offset in partner's 32)

    // ---- stage weights into LDS: wave wv stages its 32 subtiles (2g x 16s)
    for (int gate = 0; gate < 2; ++gate)
#pragma unroll
        for (int s = 0; s < 16; ++s) {
            const _Float16* gsrc = Whc +
                (size_t)(gate * 512 + j0 + wv * 16 + lrow) * 512 + s * 32 + lk * 8;
            gload_lds16(gsrc, &wlds[((wv * 2 + gate) * 16 + s) * 512]);
        }

    // ---- seed own h_0 = 0 into hlds buffer 0 (lds parity of step 0)
    *(unsigned long long*)&hlds[(lrow * 512 + jq) ^ ((lrow & 7) << 3)] = 0ull;

    // ---- izin depth-2 prefetch: E = izin[0], O = izin[1]
    QZ ez, en, oz, on;
    {
        const char* rec = izb + (size_t)blk_s * 2048 + l * 16 + wv * 8;
        ez.q = *(const unsigned long long*)(rec);
        en.q = *(const unsigned long long*)(rec + 1024);
        oz.q = *(const unsigned long long*)(rec + 262144);
        on.q = *(const unsigned long long*)(rec + 262144 + 1024);
    }

    asm volatile("s_waitcnt vmcnt(0)" ::: "memory");
    __syncthreads();

    float hm[4] = {0.f, 0.f, 0.f, 0.f};   // h[bg][jq+r] master (f32)
    const unsigned long long* hb64base = (const unsigned long long*)hbuf32;

    auto step = [&](int t, QZ& cz, QZ& cn) {
        const int par = (t + 1) & 1;           // hbuf parity holding h_t
        const int lp  = t & 1;                 // LDS buffer for h_t
        const unsigned long long tp =
            (unsigned long long)(unsigned)t | ((unsigned long long)(unsigned)t << 32);

        // ---- partner tagged burst: 15 pairs/thread (one per partner slot)
        const unsigned long long* hb64 = hb64base + (size_t)par * 32768;
        unsigned long long q0[15], q1[15];
        int pix[15];
#pragma unroll
        for (int i = 0; i < 15; ++i) {
            const int s_i = (slot + 1 + i) & 15;
            const int u32i = (16 * g + stage_b) * 512 + s_i * 32 + stage_j;
            pix[i] = u32i >> 1;
            q0[i] = __hip_atomic_load(hb64 + pix[i],     RLX, AGT);
            q1[i] = __hip_atomic_load(hb64 + pix[i] + 1, RLX, AGT);
        }
        // ---- fused retry: reload ALL partners each iteration (overlapped)
        while (true) {
            unsigned long long x = 0;
#pragma unroll
            for (int i = 0; i < 15; ++i)
                x |= (q0[i] ^ tp) | (q1[i] ^ tp);
            if (__all((x & 0x0000FFFF0000FFFFull) == 0)) break;
#pragma unroll
            for (int i = 0; i < 15; ++i) {
                q0[i] = __hip_atomic_load(hb64 + pix[i],     RLX, AGT);
                q1[i] = __hip_atomic_load(hb64 + pix[i] + 1, RLX, AGT);
            }
        }

        // ---- unpack (strip tags) + swizzled LDS stage
#pragma unroll
        for (int i = 0; i < 15; ++i) {
            const int s_i = (slot + 1 + i) & 15;
            const unsigned int w0 = ((unsigned int)(q0[i] >> 16)) & 0xFFFFu;
            const unsigned int w1 = (unsigned int)(q0[i] >> 48);
            const unsigned int w2 = ((unsigned int)(q1[i] >> 16)) & 0xFFFFu;
            const unsigned int w3 = (unsigned int)(q1[i] >> 48);
            const unsigned long long out =
                (unsigned long long)(w0 | (w1 << 16)) |
                ((unsigned long long)(w2 | (w3 << 16)) << 32);
            const int idx = (lp * 8192 + stage_b * 512 + s_i * 32 + stage_j)
                            ^ ((stage_b & 7) << 3);
            *(unsigned long long*)&hlds[idx] = out;
        }

        __syncthreads();

        // ---- MFMA: 2 tiles (z, n) x 16 k-slices; both operands from LDS
        f32x4 az = {0.f, 0.f, 0.f, 0.f}, an = {0.f, 0.f, 0.f, 0.f};
        const int hbase = lp * 8192 + lrow * 512;
        const int sw = (lrow & 7) << 3;
#pragma unroll
        for (int s = 0; s < 16; ++s) {
            const f16x8 wzv = *(const f16x8*)&wlds[((wv * 2 + 0) * 16 + s) * 512 + l * 8];
            const f16x8 wnv = *(const f16x8*)&wlds[((wv * 2 + 1) * 16 + s) * 512 + l * 8];
            const f16x8 hf  = *(const f16x8*)&hlds[(hbase + s * 32 + lk * 8) ^ sw];
            az = __builtin_amdgcn_mfma_f32_16x16x32_f16(wzv, hf, az, 0, 0, 0);
            an = __builtin_amdgcn_mfma_f32_16x16x32_f16(wnv, hf, an, 0, 0, 0);
        }

        // ---- gates + state update (f32); consumes cz/cn
        PK4 own;
        f32x4 Hv;
#pragma unroll
        for (int r = 0; r < 4; ++r) {
            float zpre = az[r] + (float)cz.v[r];
            float npre = an[r] + (float)cn.v[r];
            zpre = fminf(fmaxf(zpre, -30.f), 30.f);
            const float z = 1.f / (1.f + __expf(-zpre));
            npre = fminf(fmaxf(npre, -15.f), 15.f);
            const float e2 = __expf(2.f * npre);
            const float n = (e2 - 1.f) / (e2 + 1.f);
            hm[r] = (1.f - z) * n + z * hm[r];
            Hv[r] = hm[r];
            own.h[r] = (_Float16)hm[r];
        }

        // ---- refill this izin set with izin[t+2] (retires over next ~2 steps)
        if (t + 2 < T_LEN) {
            const char* rec = izb + ((size_t)(t + 2) * 128 + blk_s) * 2048
                              + l * 16 + wv * 8;
            cz.q = *(const unsigned long long*)rec;
            cn.q = *(const unsigned long long*)(rec + 1024);
        }
        __builtin_amdgcn_sched_barrier(0);

        // ---- stage own h_{t+1} chunk for next step (LDS parity (t+1)&1)
        *(unsigned long long*)
            &hlds[(((t + 1) & 1) * 8192 + lrow * 512 + jq) ^ ((lrow & 7) << 3)] = own.q;

        if (t < T_LEN - 1) {
            // counted drain: needs only izin[t+1] (a full step old) retired;
            // leaves the 2 just-issued izin[t+2] loads in flight.
            if (t + 2 < T_LEN) {
                asm volatile("s_waitcnt vmcnt(2)" ::: "memory");
            } else {
                asm volatile("s_waitcnt vmcnt(0)" ::: "memory");
            }
            __builtin_amdgcn_sched_barrier(0);
            const unsigned long long tagp =
                (unsigned long long)(unsigned)(t + 1) |
                ((unsigned long long)(unsigned)(t + 1) << 32);
            const unsigned long long d0 =
                ((own.q & 0xFFFFull) << 16) |
                (((own.q >> 16) & 0xFFFFull) << 48) | tagp;
            const unsigned long long d1 =
                (((own.q >> 32) & 0xFFFFull) << 16) |
                (((own.q >> 48) & 0xFFFFull) << 48) | tagp;
            unsigned long long* hw = (unsigned long long*)
                (hbuf32 + (size_t)(t & 1) * 65536 + (size_t)bg * 512 + jq);
            __hip_atomic_store(hw,     d0, RLX, AGT);
            __hip_atomic_store(hw + 1, d1, RLX, AGT);
        }

        // ---- H[t] store (fire-and-forget; safe per tag induction)
        *(f32x4*)&Hout[(size_t)t * 65536 + (size_t)bg * 512 + jq] = Hv;
    };

    for (int t = 0; t < T_LEN; t += 2) {
        step(t,     ez, en);
        step(t + 1, oz, on);
    }
}

// ---------------------------------------------------------------------------
extern "C" void kernel_launch(void* const* d_in, const int* in_sizes, int n_in,
                              void* d_out, int out_size, void* d_ws, size_t ws_size,
                              hipStream_t stream) {
    (void)in_sizes; (void)n_in; (void)out_size; (void)ws_size;
    const float* seq  = (const float*)d_in[0];
    const float* W_iz = (const float*)d_in[1];
    const float* b_iz = (const float*)d_in[2];
    const float* W_in = (const float*)d_in[3];
    const float* b_in = (const float*)d_in[4];
    const float* W_hz = (const float*)d_in[5];
    const float* b_hz = (const float*)d_in[6];
    const float* W_hn = (const float*)d_in[7];
    const float* b_hn = (const float*)d_in[8];

    char* ws = (char*)d_ws;                                 // total use: ~2.6 MB
    _Float16*     Wci    = (_Float16*)(ws);                 // 1,048,576 B
    _Float16*     Whc    = (_Float16*)(ws + 1048576);       // 1,048,576 B
    float*        bc     = (float*)   (ws + 2097152);       //     4,096 B
    unsigned int* hbuf32 = (unsigned int*)(ws + 2101248);   //   524,288 B tagged

    prep_misc<<<644, 256, 0, stream>>>(W_iz, W_in, W_hz, W_hn,
                                       b_iz, b_in, b_hz, b_hn,
                                       Wci, Whc, bc, hbuf32);
    gemm_proj<<<dim3(512, 8), 256, 0, stream>>>(seq, Wci, bc, (_Float16*)d_out);
    gru_scan<<<128, 128, 0, stream>>>(Whc, (const char*)d_out, (float*)d_out, hbuf32);
}

// Round 14
// 1958.303 us; speedup vs baseline: 1.2681x; 1.2681x over previous
//
#include <hip/hip_runtime.h>
#include <stdint.h>

typedef _Float16 f16x8 __attribute__((ext_vector_type(8)));
typedef _Float16 f16x4 __attribute__((ext_vector_type(4)));
typedef float    f32x4 __attribute__((ext_vector_type(4)));
typedef unsigned int u32x4v __attribute__((ext_vector_type(4)));

#define T_LEN 512
#define RLX   __ATOMIC_RELAXED
#define AGT   __HIP_MEMORY_SCOPE_AGENT

union PK4 { _Float16 h[4]; unsigned long long q; };
union QZ  { unsigned long long q; f16x4 v; };

// ---------------------------------------------------------------------------
// async global->LDS (16B/lane). LDS dest = wave-uniform base + lane*16.
// GLOBAL SOURCE IS PER-LANE.
// ---------------------------------------------------------------------------
__device__ __forceinline__ void gload_lds16(const void* gsrc, void* ldsdst) {
    auto g = (const __attribute__((address_space(1))) void*)(reinterpret_cast<uintptr_t>(gsrc));
    auto s = (__attribute__((address_space(3))) void*)(reinterpret_cast<uintptr_t>(ldsdst));
    __builtin_amdgcn_global_load_lds(g, s, 16, 0, 0);
}

// ---------------------------------------------------------------------------
// prep: f16 weights (Wci=[W_iz;W_in], Whc=[W_hz;W_hn]), bc=b_i+b_h,
// zero tagged hbuf (tag 0 = step-0 seed, h_0=0). Runs every launch (replays).
// ---------------------------------------------------------------------------
__global__ __launch_bounds__(256) void prep_misc(
    const float* __restrict__ W_iz, const float* __restrict__ W_in,
    const float* __restrict__ W_hz, const float* __restrict__ W_hn,
    const float* __restrict__ b_iz, const float* __restrict__ b_in,
    const float* __restrict__ b_hz, const float* __restrict__ b_hn,
    _Float16* __restrict__ Wci, _Float16* __restrict__ Whc,
    float* __restrict__ bc, unsigned int* __restrict__ hbuf32)
{
    const int tid = blockIdx.x * 256 + threadIdx.x;
    if (tid < 131072) {                      // 2 * 1024*512/8 weight vec units
        const bool is_h = tid >= 65536;
        const int u = tid & 65535;
        const int e = u * 8;
        const int row = e >> 9;
        const int k = e & 511;
        const float* s;
        if (!is_h) s = (row < 512) ? (W_iz + (size_t)row * 512 + k)
                                   : (W_in + (size_t)(row - 512) * 512 + k);
        else       s = (row < 512) ? (W_hz + (size_t)row * 512 + k)
                                   : (W_hn + (size_t)(row - 512) * 512 + k);
        f32x4 a = *(const f32x4*)s;
        f32x4 b = *(const f32x4*)(s + 4);
        f16x8 o;
        o[0] = (_Float16)a[0]; o[1] = (_Float16)a[1];
        o[2] = (_Float16)a[2]; o[3] = (_Float16)a[3];
        o[4] = (_Float16)b[0]; o[5] = (_Float16)b[1];
        o[6] = (_Float16)b[2]; o[7] = (_Float16)b[3];
        _Float16* d = is_h ? Whc : Wci;
        *(f16x8*)(d + e) = o;
    } else if (tid < 132096) {               // 1024 combined biases
        const int j2 = tid - 131072;
        bc[j2] = (j2 < 512) ? (b_iz[j2] + b_hz[j2]) : (b_in[j2 - 512] + b_hn[j2 - 512]);
    } else if (tid < 164864) {               // zero tagged hbuf: 131072 u32 / 4
        const int u = tid - 132096;
        u32x4v z = {0u, 0u, 0u, 0u};
        *(u32x4v*)(hbuf32 + (size_t)u * 4) = z;
    }
}

// ---------------------------------------------------------------------------
// Phase 1: input projections -> BLOCKED izin records (f16, into d_out):
//   record (t, blk_s) = 2KB at byte (t*128+blk_s)*2048: [z 1KB][n 1KB];
//   in-gate: lane l (64) x 16B = [quad j0+4*(l>>4), quad j0+16+4*(l>>4)],
//   b = 16*(blk_s>>4) + (l&15), j0 = 32*(blk_s&15).
// (UNCHANGED — verified rounds 4/6/8-13.)
// ---------------------------------------------------------------------------
__global__ __launch_bounds__(256) void gemm_proj(
    const float* __restrict__ A,      // seq [65536][512] f32 (row = t*128+b)
    const _Float16* __restrict__ Bw,  // Wci [1024][512] f16
    const float* __restrict__ bc,     // [1024] f32
    _Float16* Co)                     // blocked izin (= d_out as f16)
{
    __shared__ _Float16 As[128 * 40];   // padded stride 40 f16
    __shared__ _Float16 Bs[128 * 32];   // linear (global_load_lds target)

    const int mt = blockIdx.x;          // = t
    const int nt = blockIdx.y;          // 0..7 (0-3: z gate, 4-7: n gate)
    const int m0 = mt * 128, n0 = nt * 128;
    const int tid = threadIdx.x;
    const int w = tid >> 6, l = tid & 63;
    const int wr = w >> 1, wc = w & 1;
    const int lrow = l & 15, lk = l >> 4;

    f32x4 acc[4][4] = {};

    const int arow = tid >> 1;
    const int acol = (tid & 1) * 16;

    for (int kt = 0; kt < 16; ++kt) {
        const int k0 = kt * 32;
        if (kt) __syncthreads();
        const float* as = A + (size_t)(m0 + arow) * 512 + k0 + acol;
        f32x4 a0 = *(const f32x4*)as;
        f32x4 a1 = *(const f32x4*)(as + 4);
        f32x4 a2 = *(const f32x4*)(as + 8);
        f32x4 a3 = *(const f32x4*)(as + 12);
        f16x8 h0, h1;
#pragma unroll
        for (int e = 0; e < 4; ++e) {
            h0[e] = (_Float16)a0[e]; h0[4 + e] = (_Float16)a1[e];
            h1[e] = (_Float16)a2[e]; h1[4 + e] = (_Float16)a3[e];
        }
        *(f16x8*)&As[arow * 40 + acol] = h0;
        *(f16x8*)&As[arow * 40 + acol + 8] = h1;
#pragma unroll
        for (int i = 0; i < 2; ++i) {
            const int chunk = w * 2 + i;
            const _Float16* gsrc =
                Bw + (size_t)(n0 + chunk * 16 + (l >> 2)) * 512 + k0 + (l & 3) * 8;
            gload_lds16(gsrc, &Bs[chunk * 512]);
        }
        __syncthreads();
        f16x8 af[4], bf[4];
#pragma unroll
        for (int i = 0; i < 4; ++i) {
            af[i] = *(const f16x8*)&As[(wr * 64 + i * 16 + lrow) * 40 + lk * 8];
            bf[i] = *(const f16x8*)&Bs[(wc * 64 + i * 16 + lrow) * 32 + lk * 8];
        }
#pragma unroll
        for (int mi = 0; mi < 4; ++mi)
#pragma unroll
            for (int ni = 0; ni < 4; ++ni)
                acc[mi][ni] = __builtin_amdgcn_mfma_f32_16x16x32_f16(
                    bf[ni], af[mi], acc[mi][ni], 0, 0, 0);
    }
    // epilogue: bias + cvt f16 + blocked store
    const int gate = nt >> 2;
#pragma unroll
    for (int mi = 0; mi < 4; ++mi) {
#pragma unroll
        for (int p = 0; p < 2; ++p) {
            const int j2q0 = n0 + wc * 64 + p * 32 + 4 * lk;
            const f32x4 b0 = *(const f32x4*)&bc[j2q0];
            const f32x4 b1 = *(const f32x4*)&bc[j2q0 + 16];
            f16x8 o;
#pragma unroll
            for (int r = 0; r < 4; ++r) {
                o[r]     = (_Float16)(acc[mi][2 * p][r]     + b0[r]);
                o[4 + r] = (_Float16)(acc[mi][2 * p + 1][r] + b1[r]);
            }
            const int blk_s = (wr * 4 + mi) * 16 + (nt & 3) * 4 + wc * 2 + p;
            _Float16* dst = Co + ((((size_t)mt * 128 + blk_s) * 2 + gate) * 512) + l * 8;
            *(f16x8*)dst = o;
        }
    }
}

// ---------------------------------------------------------------------------
// Phase 2: persistent scan — 32 WGs x 8 waves (512 thr). R12 structure
// (best measured: 1672 us) with ONE change: weight fragments pinned in
// AGPRS via asm "a" constraints. Rationale: at 8 waves/CU the ARCH VGPR
// file can't hold 128 weight regs + working set (R9-12: VGPR_Count 96-116,
// weights spilled/remat -> 256 KB/CU/step through L2 ~= 1.9 us/step). The
// gfx950 unified file supports 256 regs/wave at 8 waves/CU (m69), and MFMA
// reads A/B directly from AGPRs (cdna4_isa §10) — so 128 AGPRs hold the
// weights with zero per-step memory traffic. Verification: VGPR_Count
// should jump ~116 -> ~230-256.
// ---------------------------------------------------------------------------
__global__ __launch_bounds__(512, 1) void gru_scan(
    const _Float16* __restrict__ Whc,   // [1024][512] f16
    const char* izb,                    // d_out bytes: blocked izin (aliases Hout)
    float* Hout,                        // d_out as f32 [t][b][j]
    unsigned int* hbuf32)               // [2][128][512] tagged u32
{
    __shared__ _Float16 hlds[2 * 16 * 512];   // 32 KB, XOR-swizzled (^(b&7)<<3)

    const int blk  = blockIdx.x;        // 0..31
    const int g    = blk & 7;
    const int slot = blk >> 3;          // 0..3
    const int tid  = threadIdx.x;
    const int wv   = tid >> 6;          // wave 0..7
    const int l    = tid & 63;
    const int lrow = l & 15, lk = l >> 4;
    const int jbase = slot * 128 + wv * 16;
    const int jq    = jbase + 4 * lk;            // lane's j quad base
    const int bg    = 16 * g + lrow;             // lane's global b (frag row)
    const int blk_s = 16 * g + 4 * slot + (wv >> 1);  // izin record index
    const int stage_b = tid >> 5;                // 0..15 (partner staging b)
    const int stage_jq = 4 * (tid & 31);         // 0..124 (partner staging j-quad)

    // ---- weights: loaded once, pinned in AGPRs (see header)
    f16x8 wz[16], wn[16];
#pragma unroll
    for (int s = 0; s < 16; ++s) {
        wz[s] = *(const f16x8*)&Whc[(size_t)(jbase + lrow) * 512 + s * 32 + lk * 8];
        wn[s] = *(const f16x8*)&Whc[(size_t)(512 + jbase + lrow) * 512 + s * 32 + lk * 8];
    }
#pragma unroll
    for (int s = 0; s < 16; ++s) {
        asm volatile("" : "+a"(wz[s]));
        asm volatile("" : "+a"(wn[s]));
    }

    // ---- seed own h_0 = 0 into hlds[0] (parity of step 0)
    *(unsigned long long*)&hlds[(lrow * 512 + jq) ^ ((lrow & 7) << 3)] = 0ull;

    // ---- izin prefetch depth 2: set E = izin[0], set O = izin[1]
    QZ ez, en, oz, on;
    {
        const char* r0 = izb + ((size_t)0 * 128 + blk_s) * 2048 + l * 16 + (wv & 1) * 8;
        ez.q = *(const unsigned long long*)r0;
        en.q = *(const unsigned long long*)(r0 + 1024);
        const char* r1 = izb + ((size_t)1 * 128 + blk_s) * 2048 + l * 16 + (wv & 1) * 8;
        oz.q = *(const unsigned long long*)r1;
        on.q = *(const unsigned long long*)(r1 + 1024);
    }

    float hm[4] = {0.f, 0.f, 0.f, 0.f};   // h[bg][jq+r] master (f32)

    const unsigned long long* hb64base = (const unsigned long long*)hbuf32;

    // ---------------- one scan step (consumes cz/cn, refills with izin[t+2])
    auto step = [&](int t, QZ& cz, QZ& cn) {
        const int par = (t + 1) & 1;           // parity holding h_t
        const int lp  = t & 1;                 // LDS buffer for h_t
        const unsigned long long tp =
            (unsigned long long)(unsigned)t | ((unsigned long long)(unsigned)t << 32);

        // ---- partner tagged loads: 3 quads/thread (one per partner slot)
        const unsigned long long* hb64 = hb64base + (size_t)par * 32768;
        unsigned long long q0[3], q1[3];
        int pix[3];
#pragma unroll
        for (int i = 0; i < 3; ++i) {
            const int s_i = (slot + 1 + i) & 3;
            const int u32i = (16 * g + stage_b) * 512 + s_i * 128 + stage_jq;
            pix[i] = u32i >> 1;
            q0[i] = __hip_atomic_load(hb64 + pix[i],     RLX, AGT);
            q1[i] = __hip_atomic_load(hb64 + pix[i] + 1, RLX, AGT);
        }
        // ---- FUSED retry: one iteration = reload ALL partners (overlapped)
        while (true) {
            unsigned long long x = 0;
#pragma unroll
            for (int i = 0; i < 3; ++i)
                x |= (q0[i] ^ tp) | (q1[i] ^ tp);
            if (__all((x & 0x0000FFFF0000FFFFull) == 0)) break;
#pragma unroll
            for (int i = 0; i < 3; ++i) {
                q0[i] = __hip_atomic_load(hb64 + pix[i],     RLX, AGT);
                q1[i] = __hip_atomic_load(hb64 + pix[i] + 1, RLX, AGT);
            }
        }

        // ---- unpack (strip tags) + swizzled LDS stage
#pragma unroll
        for (int i = 0; i < 3; ++i) {
            const int s_i = (slot + 1 + i) & 3;
            const unsigned int w0 = ((unsigned int)(q0[i] >> 16)) & 0xFFFFu;
            const unsigned int w1 = (unsigned int)(q0[i] >> 48);
            const unsigned int w2 = ((unsigned int)(q1[i] >> 16)) & 0xFFFFu;
            const unsigned int w3 = (unsigned int)(q1[i] >> 48);
            const unsigned long long out =
                (unsigned long long)(w0 | (w1 << 16)) |
                ((unsigned long long)(w2 | (w3 << 16)) << 32);
            const int idx = (lp * 8192 + stage_b * 512 + s_i * 128 + stage_jq)
                            ^ ((stage_b & 7) << 3);
            *(unsigned long long*)&hlds[idx] = out;
        }

        __syncthreads();

        // ---- MFMA: 2 tiles (z, n) x 16 k-slices; weights from AGPRs
        f32x4 az = {0.f, 0.f, 0.f, 0.f}, an = {0.f, 0.f, 0.f, 0.f};
        const int hbase = lp * 8192 + lrow * 512;
        const int sw = (lrow & 7) << 3;
#pragma unroll
        for (int s = 0; s < 16; ++s) {
            asm volatile("" : "+a"(wz[s]), "+a"(wn[s]));   // keep AGPR-resident
            const f16x8 hf = *(const f16x8*)&hlds[(hbase + s * 32 + lk * 8) ^ sw];
            az = __builtin_amdgcn_mfma_f32_16x16x32_f16(wz[s], hf, az, 0, 0, 0);
            an = __builtin_amdgcn_mfma_f32_16x16x32_f16(wn[s], hf, an, 0, 0, 0);
        }

        // ---- gates + state update (f32); consumes cz/cn
        PK4 own;
        f32x4 Hv;
#pragma unroll
        for (int r = 0; r < 4; ++r) {
            float zpre = az[r] + (float)cz.v[r];
            float npre = an[r] + (float)cn.v[r];
            zpre = fminf(fmaxf(zpre, -30.f), 30.f);
            const float z = 1.f / (1.f + __expf(-zpre));
            npre = fminf(fmaxf(npre, -15.f), 15.f);
            const float e2 = __expf(2.f * npre);
            const float n = (e2 - 1.f) / (e2 + 1.f);
            hm[r] = (1.f - z) * n + z * hm[r];
            Hv[r] = hm[r];
            own.h[r] = (_Float16)hm[r];
        }

        // ---- refill this set with izin[t+2] (retires over the next ~2 steps)
        if (t + 2 < T_LEN) {
            const char* rec = izb + ((size_t)(t + 2) * 128 + blk_s) * 2048
                              + l * 16 + (wv & 1) * 8;
            cz.q = *(const unsigned long long*)rec;
            cn.q = *(const unsigned long long*)(rec + 1024);
        }
        __builtin_amdgcn_sched_barrier(0);

        // ---- stage own h_{t+1} chunk for next step (LDS parity (t+1)&1)
        *(unsigned long long*)
            &hlds[(((t + 1) & 1) * 8192 + lrow * 512 + jq) ^ ((lrow & 7) << 3)] = own.q;

        if (t < T_LEN - 1) {
            // counted drain: only needs izin[t+1] (a full step old) retired;
            // leaves the 2 izin[t+2] loads in flight.
            if (t + 2 < T_LEN) {
                asm volatile("s_waitcnt vmcnt(2)" ::: "memory");
            } else {
                asm volatile("s_waitcnt vmcnt(0)" ::: "memory");
            }
            __builtin_amdgcn_sched_barrier(0);
            const unsigned long long tagp =
                (unsigned long long)(unsigned)(t + 1) |
                ((unsigned long long)(unsigned)(t + 1) << 32);
            const unsigned long long d0 =
                ((own.q & 0xFFFFull) << 16) |
                (((own.q >> 16) & 0xFFFFull) << 48) | tagp;
            const unsigned long long d1 =
                (((own.q >> 32) & 0xFFFFull) << 16) |
                (((own.q >> 48) & 0xFFFFull) << 48) | tagp;
            unsigned long long* hw = (unsigned long long*)
                (hbuf32 + (size_t)(t & 1) * 65536 + (size_t)bg * 512 + jq);
            __hip_atomic_store(hw,     d0, RLX, AGT);
            __hip_atomic_store(hw + 1, d1, RLX, AGT);
        }

        // ---- H[t] store (fire-and-forget; safe: all tags==t seen pre-barrier)
        *(f32x4*)&Hout[(size_t)t * 65536 + (size_t)bg * 512 + jq] = Hv;
    };

    for (int t = 0; t < T_LEN; t += 2) {
        step(t,     ez, en);
        step(t + 1, oz, on);
    }
}

// ---------------------------------------------------------------------------
extern "C" void kernel_launch(void* const* d_in, const int* in_sizes, int n_in,
                              void* d_out, int out_size, void* d_ws, size_t ws_size,
                              hipStream_t stream) {
    (void)in_sizes; (void)n_in; (void)out_size; (void)ws_size;
    const float* seq  = (const float*)d_in[0];
    const float* W_iz = (const float*)d_in[1];
    const float* b_iz = (const float*)d_in[2];
    const float* W_in = (const float*)d_in[3];
    const float* b_in = (const float*)d_in[4];
    const float* W_hz = (const float*)d_in[5];
    const float* b_hz = (const float*)d_in[6];
    const float* W_hn = (const float*)d_in[7];
    const float* b_hn = (const float*)d_in[8];

    char* ws = (char*)d_ws;                                 // total use: ~2.6 MB
    _Float16*     Wci    = (_Float16*)(ws);                 // 1,048,576 B
    _Float16*     Whc    = (_Float16*)(ws + 1048576);       // 1,048,576 B
    float*        bc     = (float*)   (ws + 2097152);       //     4,096 B
    unsigned int* hbuf32 = (unsigned int*)(ws + 2101248);   //   524,288 B tagged

    prep_misc<<<644, 256, 0, stream>>>(W_iz, W_in, W_hz, W_hn,
                                       b_iz, b_in, b_hz, b_hn,
                                       Wci, Whc, bc, hbuf32);
    gemm_proj<<<dim3(512, 8), 256, 0, stream>>>(seq, Wci, bc, (_Float16*)d_out);
    gru_scan<<<32, 512, 0, stream>>>(Whc, (const char*)d_out, (float*)d_out, hbuf32);
}